// Round 3
// baseline (1594.653 us; speedup 1.0000x reference)
//
#include <hip/hip_runtime.h>
#include <hip/hip_bf16.h>

// TinySelfAttention: x[2,2048,1024] fp32; Wq/Wk/Wv/Wo [1024,1024] fp32 ([out,in]).
// out = softmax_causal((xWq^T)(xWk^T)^T/8) (xWv^T) Wo^T, fp32.
//
// Pipeline: cast x,W -> bf16 | 3x MFMA GEMM (Q,K,V bf16) | fp32 flash attention
//           (writes y bf16) | MFMA GEMM y@Wo^T -> fp32 d_out.
// Workspace: 48 MB (xb 8 + W 8 + QKV 24 + y 8).

#define S_LEN  2048
#define BATCH  2
#define DMODEL 1024
#define NHEADS 16
#define HDIM   64

typedef short short8 __attribute__((ext_vector_type(8)));
typedef float f32x4  __attribute__((ext_vector_type(4)));

__device__ __forceinline__ float b2f(unsigned short u) {
    union { unsigned int i; float f; } x; x.i = ((unsigned int)u) << 16; return x.f;
}
__device__ __forceinline__ unsigned short f2b(float f) {
    union { float f; unsigned int i; } x; x.f = f;
    unsigned int r = x.i + 0x7fffu + ((x.i >> 16) & 1u);  // RNE
    return (unsigned short)(r >> 16);
}

// ---------------- cast fp32 -> bf16, 4 elems/thread ----------------
__global__ void cast_kernel(const float* __restrict__ in, unsigned short* __restrict__ out, int n4) {
    int i = blockIdx.x * blockDim.x + threadIdx.x;
    if (i >= n4) return;
    float4 v = ((const float4*)in)[i];
    unsigned int lo = (unsigned int)f2b(v.x) | ((unsigned int)f2b(v.y) << 16);
    unsigned int hi = (unsigned int)f2b(v.z) | ((unsigned int)f2b(v.w) << 16);
    ((uint2*)out)[i] = make_uint2(lo, hi);
}

// ---------------- bf16 MFMA GEMM: C[M,N] = A[M,K] @ W[N,K]^T ----------------
// 64x64 tile, BK=64, 256 threads (4 waves, 2x2 of 32x32), LDS stride 80 (bank fix).
template<int OUT_BF16>
__global__ __launch_bounds__(256) void gemm_nt(const unsigned short* __restrict__ A,
                                               const unsigned short* __restrict__ W,
                                               unsigned short* __restrict__ Cb,
                                               float* __restrict__ Cf,
                                               int M, int N, int K) {
    (void)M;
    __shared__ unsigned short As[64][80];
    __shared__ unsigned short Bs[64][80];
    const int tid  = threadIdx.x;
    const int lane = tid & 63;
    const int wave = tid >> 6;
    const int bm = blockIdx.y * 64;
    const int bn = blockIdx.x * 64;
    const int wr = (wave >> 1) * 32;
    const int wc = (wave & 1) * 32;
    const int l15 = lane & 15;
    const int l4  = lane >> 4;
    const int srow = tid >> 2;            // 0..63
    const int sk   = (tid & 3) * 16;      // 0,16,32,48 (shorts)

    f32x4 acc[2][2];
#pragma unroll
    for (int i = 0; i < 2; ++i)
#pragma unroll
        for (int j = 0; j < 2; ++j) acc[i][j] = (f32x4){0.f,0.f,0.f,0.f};

    const unsigned short* Arow = A + (size_t)(bm + srow) * K + sk;
    const unsigned short* Wrow = W + (size_t)(bn + srow) * K + sk;

    for (int k0 = 0; k0 < K; k0 += 64) {
        uint4 a0 = *(const uint4*)(Arow + k0);
        uint4 a1 = *(const uint4*)(Arow + k0 + 8);
        uint4 b0 = *(const uint4*)(Wrow + k0);
        uint4 b1 = *(const uint4*)(Wrow + k0 + 8);
        __syncthreads();   // protect previous iteration's fragment reads
        *(uint4*)&As[srow][sk]     = a0;
        *(uint4*)&As[srow][sk + 8] = a1;
        *(uint4*)&Bs[srow][sk]     = b0;
        *(uint4*)&Bs[srow][sk + 8] = b1;
        __syncthreads();
#pragma unroll
        for (int kk = 0; kk < 2; ++kk) {
            short8 af0 = *(const short8*)&As[wr + l15]     [kk*32 + l4*8];
            short8 af1 = *(const short8*)&As[wr + 16 + l15][kk*32 + l4*8];
            short8 bf0 = *(const short8*)&Bs[wc + l15]     [kk*32 + l4*8];
            short8 bf1 = *(const short8*)&Bs[wc + 16 + l15][kk*32 + l4*8];
            acc[0][0] = __builtin_amdgcn_mfma_f32_16x16x32_bf16(af0, bf0, acc[0][0], 0, 0, 0);
            acc[0][1] = __builtin_amdgcn_mfma_f32_16x16x32_bf16(af0, bf1, acc[0][1], 0, 0, 0);
            acc[1][0] = __builtin_amdgcn_mfma_f32_16x16x32_bf16(af1, bf0, acc[1][0], 0, 0, 0);
            acc[1][1] = __builtin_amdgcn_mfma_f32_16x16x32_bf16(af1, bf1, acc[1][1], 0, 0, 0);
        }
    }
    // epilogue: C/D layout col=lane&15, row=(lane>>4)*4+i (HW-verified)
#pragma unroll
    for (int mi = 0; mi < 2; ++mi)
#pragma unroll
        for (int ni = 0; ni < 2; ++ni)
#pragma unroll
            for (int i = 0; i < 4; ++i) {
                int row = bm + wr + mi*16 + l4*4 + i;
                int col = bn + wc + ni*16 + l15;
                float v = acc[mi][ni][i];
                if constexpr (OUT_BF16) Cb[(size_t)row * N + col] = f2b(v);
                else                    Cf[(size_t)row * N + col] = v;
            }
}

// ---------------- fp32 flash attention (causal), one block = 64 queries of one (b,h) ----------------
// 256 threads: 4 threads per query row; thread owns keys k = (tid&3)+4j, j=0..15.
__global__ __launch_bounds__(256) void attn_kernel(const unsigned short* __restrict__ Qp,
                                                   const unsigned short* __restrict__ Kp,
                                                   const unsigned short* __restrict__ Vp,
                                                   unsigned short* __restrict__ Yp) {
    __shared__ float Ks[64][68];
    __shared__ float Vs[64][68];
    const int tid = threadIdx.x;
    const int qt = blockIdx.x, h = blockIdx.y, b = blockIdx.z;
    const int r  = tid >> 2;       // query row in tile
    const int c4 = tid & 3;        // key/dim sub-owner
    const int qg = qt * 64 + r;

    // q row -> registers, pre-scaled by 1/sqrt(64)
    float q[64];
    {
        const unsigned short* qrow = Qp + ((size_t)(b * S_LEN + qg)) * DMODEL + h * HDIM;
#pragma unroll
        for (int c = 0; c < 8; ++c) {
            uint4 u = *(const uint4*)(qrow + c * 8);
            const unsigned short* us = (const unsigned short*)&u;
#pragma unroll
            for (int i = 0; i < 8; ++i) q[c*8 + i] = b2f(us[i]) * 0.125f;
        }
    }

    float acc[64];
#pragma unroll
    for (int d = 0; d < 64; ++d) acc[d] = 0.f;
    float m = -1e30f, l = 0.f;

    for (int kt = 0; kt <= qt; ++kt) {
        __syncthreads();   // previous tile's LDS reads done
        {   // stage K,V tile (bf16 -> fp32), thread: row r, dims c4*16..+15
            const size_t base = ((size_t)(b * S_LEN + kt * 64 + r)) * DMODEL + h * HDIM + c4 * 16;
            uint4 ku0 = *(const uint4*)(Kp + base);
            uint4 ku1 = *(const uint4*)(Kp + base + 8);
            uint4 vu0 = *(const uint4*)(Vp + base);
            uint4 vu1 = *(const uint4*)(Vp + base + 8);
            const int sd = c4 * 16;
            const unsigned short* us;
            us = (const unsigned short*)&ku0;
            *(float4*)&Ks[r][sd+0]  = make_float4(b2f(us[0]),b2f(us[1]),b2f(us[2]),b2f(us[3]));
            *(float4*)&Ks[r][sd+4]  = make_float4(b2f(us[4]),b2f(us[5]),b2f(us[6]),b2f(us[7]));
            us = (const unsigned short*)&ku1;
            *(float4*)&Ks[r][sd+8]  = make_float4(b2f(us[0]),b2f(us[1]),b2f(us[2]),b2f(us[3]));
            *(float4*)&Ks[r][sd+12] = make_float4(b2f(us[4]),b2f(us[5]),b2f(us[6]),b2f(us[7]));
            us = (const unsigned short*)&vu0;
            *(float4*)&Vs[r][sd+0]  = make_float4(b2f(us[0]),b2f(us[1]),b2f(us[2]),b2f(us[3]));
            *(float4*)&Vs[r][sd+4]  = make_float4(b2f(us[4]),b2f(us[5]),b2f(us[6]),b2f(us[7]));
            us = (const unsigned short*)&vu1;
            *(float4*)&Vs[r][sd+8]  = make_float4(b2f(us[0]),b2f(us[1]),b2f(us[2]),b2f(us[3]));
            *(float4*)&Vs[r][sd+12] = make_float4(b2f(us[4]),b2f(us[5]),b2f(us[6]),b2f(us[7]));
        }
        __syncthreads();

        // scores for this thread's 16 keys
        float pj[16];
        float tmax = -1e30f;
#pragma unroll
        for (int j = 0; j < 16; ++j) {
            const int k = c4 + 4 * j;
            float s = 0.f;
#pragma unroll
            for (int d0 = 0; d0 < 16; ++d0) {
                float4 kv = *(const float4*)&Ks[k][d0 * 4];
                s += q[d0*4+0]*kv.x + q[d0*4+1]*kv.y + q[d0*4+2]*kv.z + q[d0*4+3]*kv.w;
            }
            const int kg = kt * 64 + k;
            s = (kg <= qg) ? s : -1e30f;
            pj[j] = s;
            tmax = fmaxf(tmax, s);
        }
        // row max across the 4 owner lanes (consecutive lanes, same wave)
        tmax = fmaxf(tmax, __shfl_xor(tmax, 1));
        tmax = fmaxf(tmax, __shfl_xor(tmax, 2));
        const float mn = fmaxf(m, tmax);
        const float alpha = __expf(m - mn);   // first tile: exp(-huge)=0
        float lsum = 0.f;
#pragma unroll
        for (int j = 0; j < 16; ++j) { pj[j] = __expf(pj[j] - mn); lsum += pj[j]; }
        lsum += __shfl_xor(lsum, 1);
        lsum += __shfl_xor(lsum, 2);
        l = l * alpha + lsum;
#pragma unroll
        for (int d = 0; d < 64; ++d) acc[d] *= alpha;
        // PV
#pragma unroll
        for (int j = 0; j < 16; ++j) {
            const int k = c4 + 4 * j;
            const float p = pj[j];
#pragma unroll
            for (int d0 = 0; d0 < 16; ++d0) {
                float4 vv = *(const float4*)&Vs[k][d0 * 4];
                acc[d0*4+0] += p * vv.x; acc[d0*4+1] += p * vv.y;
                acc[d0*4+2] += p * vv.z; acc[d0*4+3] += p * vv.w;
            }
        }
        m = mn;
    }

    // sum partial accumulators across the 4 owner lanes
#pragma unroll
    for (int d = 0; d < 64; ++d) {
        float v = acc[d];
        v += __shfl_xor(v, 1);
        v += __shfl_xor(v, 2);
        acc[d] = v;
    }
    const float linv = 1.0f / l;   // l identical across the 4 lanes
    // extract this thread's 16-dim slice with compile-time indices only
    unsigned int pk[8];
#pragma unroll
    for (int i = 0; i < 8; ++i) pk[i] = 0u;
#pragma unroll
    for (int dd = 0; dd < 64; dd += 2) {
        unsigned int w = (unsigned int)f2b(acc[dd] * linv) |
                         ((unsigned int)f2b(acc[dd+1] * linv) << 16);
        const int slot = (dd & 15) >> 1;          // compile-time
        pk[slot] = ((dd >> 4) == c4) ? w : pk[slot];
    }
    unsigned short* yrow = Yp + ((size_t)(b * S_LEN + qg)) * DMODEL + h * HDIM + c4 * 16;
    *(uint4*)(yrow)     = make_uint4(pk[0], pk[1], pk[2], pk[3]);
    *(uint4*)(yrow + 8) = make_uint4(pk[4], pk[5], pk[6], pk[7]);
}

extern "C" void kernel_launch(void* const* d_in, const int* in_sizes, int n_in,
                              void* d_out, int out_size, void* d_ws, size_t ws_size,
                              hipStream_t stream) {
    (void)in_sizes; (void)n_in; (void)out_size; (void)ws_size;
    const float* x  = (const float*)d_in[0];
    const float* Wq = (const float*)d_in[1];
    const float* Wk = (const float*)d_in[2];
    const float* Wv = (const float*)d_in[3];
    const float* Wo = (const float*)d_in[4];
    float* out = (float*)d_out;

    const size_t nx = (size_t)BATCH * S_LEN * DMODEL;   // 4,194,304
    const size_t nw = (size_t)DMODEL * DMODEL;          // 1,048,576
    char* ws = (char*)d_ws;
    unsigned short* xb  = (unsigned short*)ws; ws += nx * 2;
    unsigned short* wqb = (unsigned short*)ws; ws += nw * 2;
    unsigned short* wkb = (unsigned short*)ws; ws += nw * 2;
    unsigned short* wvb = (unsigned short*)ws; ws += nw * 2;
    unsigned short* wob = (unsigned short*)ws; ws += nw * 2;
    unsigned short* Qp  = (unsigned short*)ws; ws += nx * 2;
    unsigned short* Kp  = (unsigned short*)ws; ws += nx * 2;
    unsigned short* Vp  = (unsigned short*)ws; ws += nx * 2;
    unsigned short* yb  = (unsigned short*)ws; ws += nx * 2;  // total 48 MB

    cast_kernel<<<(int)(nx/4 + 255)/256, 256, 0, stream>>>(x,  xb,  (int)(nx/4));
    cast_kernel<<<(int)(nw/4 + 255)/256, 256, 0, stream>>>(Wq, wqb, (int)(nw/4));
    cast_kernel<<<(int)(nw/4 + 255)/256, 256, 0, stream>>>(Wk, wkb, (int)(nw/4));
    cast_kernel<<<(int)(nw/4 + 255)/256, 256, 0, stream>>>(Wv, wvb, (int)(nw/4));
    cast_kernel<<<(int)(nw/4 + 255)/256, 256, 0, stream>>>(Wo, wob, (int)(nw/4));

    dim3 gg(DMODEL / 64, (BATCH * S_LEN) / 64);
    gemm_nt<1><<<gg, 256, 0, stream>>>(xb, wqb, Qp, nullptr, BATCH*S_LEN, DMODEL, DMODEL);
    gemm_nt<1><<<gg, 256, 0, stream>>>(xb, wkb, Kp, nullptr, BATCH*S_LEN, DMODEL, DMODEL);
    gemm_nt<1><<<gg, 256, 0, stream>>>(xb, wvb, Vp, nullptr, BATCH*S_LEN, DMODEL, DMODEL);

    dim3 ga(S_LEN / 64, NHEADS, BATCH);
    attn_kernel<<<ga, 256, 0, stream>>>(Qp, Kp, Vp, yb);

    gemm_nt<0><<<gg, 256, 0, stream>>>(yb, wob, nullptr, out, BATCH*S_LEN, DMODEL, DMODEL);
}

// Round 4
// 244.896 us; speedup vs baseline: 6.5115x; 6.5115x over previous
//
#include <hip/hip_runtime.h>
#include <hip/hip_bf16.h>

// TinySelfAttention: x[2,2048,1024] fp32; Wq/Wk/Wv/Wo [1024,1024] fp32 ([out,in]).
// out = softmax_causal((xWq^T)(xWk^T)^T/8) (xWv^T) Wo^T, fp32.
//
// Pipeline: cast x,W -> bf16 | 3x MFMA GEMM (Q,K,V bf16) | bf16 MFMA flash attention
//           (writes y bf16) | MFMA GEMM y@Wo^T -> fp32 d_out.

#define S_LEN  2048
#define BATCH  2
#define DMODEL 1024
#define NHEADS 16
#define HDIM   64

typedef short short8 __attribute__((ext_vector_type(8)));
typedef float f32x4  __attribute__((ext_vector_type(4)));

__device__ __forceinline__ float b2f(unsigned short u) {
    union { unsigned int i; float f; } x; x.i = ((unsigned int)u) << 16; return x.f;
}
__device__ __forceinline__ unsigned short f2b(float f) {
    union { float f; unsigned int i; } x; x.f = f;
    unsigned int r = x.i + 0x7fffu + ((x.i >> 16) & 1u);  // RNE
    return (unsigned short)(r >> 16);
}

// XOR-swizzled accessor for 128B-row LDS tiles (G4 bank-conflict fix).
// byte-in-row ^= ((row ^ row>>3) & 7) << 4 : bijective per row, keeps 16B align.
__device__ __forceinline__ unsigned short* swzp(unsigned short* base, int row, int col) {
    int byte = (col << 1) ^ ((((row >> 3) ^ row) & 7) << 4);
    return base + (row << 6) + (byte >> 1);
}

// ---------------- cast fp32 -> bf16, 4 elems/thread ----------------
__global__ void cast_kernel(const float* __restrict__ in, unsigned short* __restrict__ out, int n4) {
    int i = blockIdx.x * blockDim.x + threadIdx.x;
    if (i >= n4) return;
    float4 v = ((const float4*)in)[i];
    unsigned int lo = (unsigned int)f2b(v.x) | ((unsigned int)f2b(v.y) << 16);
    unsigned int hi = (unsigned int)f2b(v.z) | ((unsigned int)f2b(v.w) << 16);
    ((uint2*)out)[i] = make_uint2(lo, hi);
}

// ---------------- bf16 MFMA GEMM: C[M,N] = A[M,K] @ W[N,K]^T ----------------
// 64x64 tile, BK=64, 256 threads (4 waves, 2x2 of 32x32), LDS stride 80 (bank fix).
template<int OUT_BF16>
__global__ __launch_bounds__(256) void gemm_nt(const unsigned short* __restrict__ A,
                                               const unsigned short* __restrict__ W,
                                               unsigned short* __restrict__ Cb,
                                               float* __restrict__ Cf,
                                               int M, int N, int K) {
    (void)M;
    __shared__ unsigned short As[64][80];
    __shared__ unsigned short Bs[64][80];
    const int tid  = threadIdx.x;
    const int lane = tid & 63;
    const int wave = tid >> 6;
    const int bm = blockIdx.y * 64;
    const int bn = blockIdx.x * 64;
    const int wr = (wave >> 1) * 32;
    const int wc = (wave & 1) * 32;
    const int l15 = lane & 15;
    const int l4  = lane >> 4;
    const int srow = tid >> 2;            // 0..63
    const int sk   = (tid & 3) * 16;      // 0,16,32,48 (shorts)

    f32x4 acc[2][2];
#pragma unroll
    for (int i = 0; i < 2; ++i)
#pragma unroll
        for (int j = 0; j < 2; ++j) acc[i][j] = (f32x4){0.f,0.f,0.f,0.f};

    const unsigned short* Arow = A + (size_t)(bm + srow) * K + sk;
    const unsigned short* Wrow = W + (size_t)(bn + srow) * K + sk;

    for (int k0 = 0; k0 < K; k0 += 64) {
        uint4 a0 = *(const uint4*)(Arow + k0);
        uint4 a1 = *(const uint4*)(Arow + k0 + 8);
        uint4 b0 = *(const uint4*)(Wrow + k0);
        uint4 b1 = *(const uint4*)(Wrow + k0 + 8);
        __syncthreads();   // protect previous iteration's fragment reads
        *(uint4*)&As[srow][sk]     = a0;
        *(uint4*)&As[srow][sk + 8] = a1;
        *(uint4*)&Bs[srow][sk]     = b0;
        *(uint4*)&Bs[srow][sk + 8] = b1;
        __syncthreads();
#pragma unroll
        for (int kk = 0; kk < 2; ++kk) {
            short8 af0 = *(const short8*)&As[wr + l15]     [kk*32 + l4*8];
            short8 af1 = *(const short8*)&As[wr + 16 + l15][kk*32 + l4*8];
            short8 bf0 = *(const short8*)&Bs[wc + l15]     [kk*32 + l4*8];
            short8 bf1 = *(const short8*)&Bs[wc + 16 + l15][kk*32 + l4*8];
            acc[0][0] = __builtin_amdgcn_mfma_f32_16x16x32_bf16(af0, bf0, acc[0][0], 0, 0, 0);
            acc[0][1] = __builtin_amdgcn_mfma_f32_16x16x32_bf16(af0, bf1, acc[0][1], 0, 0, 0);
            acc[1][0] = __builtin_amdgcn_mfma_f32_16x16x32_bf16(af1, bf0, acc[1][0], 0, 0, 0);
            acc[1][1] = __builtin_amdgcn_mfma_f32_16x16x32_bf16(af1, bf1, acc[1][1], 0, 0, 0);
        }
    }
    // epilogue: C/D layout col=lane&15, row=(lane>>4)*4+i (HW-verified)
#pragma unroll
    for (int mi = 0; mi < 2; ++mi)
#pragma unroll
        for (int ni = 0; ni < 2; ++ni)
#pragma unroll
            for (int i = 0; i < 4; ++i) {
                int row = bm + wr + mi*16 + l4*4 + i;
                int col = bn + wc + ni*16 + l15;
                float v = acc[mi][ni][i];
                if constexpr (OUT_BF16) Cb[(size_t)row * N + col] = f2b(v);
                else                    Cf[(size_t)row * N + col] = v;
            }
}

// ---------------- bf16 MFMA flash attention (causal) ----------------
// Block = (b, h, folded q-tile pair {f, 31-f}) -> uniform 33 kv-tiles/block.
// 4 waves x 16 q-rows. QK^T and PV on mfma_f32_16x16x32_bf16.
// K, V^T staged bf16 in swizzled LDS; P relayout via wave-private LDS.
__global__ __launch_bounds__(256) void attn_mfma(const unsigned short* __restrict__ Qp,
                                                 const unsigned short* __restrict__ Kp,
                                                 const unsigned short* __restrict__ Vp,
                                                 unsigned short* __restrict__ Yp) {
    __shared__ unsigned short Ks[64 * 64];   // K[key][d]
    __shared__ unsigned short Vt[64 * 64];   // V^T[d][key]
    __shared__ unsigned short Pl[4 * 16 * 64]; // per-wave P[q][key]
    const int tid  = threadIdx.x;
    const int lane = tid & 63;
    const int wq   = tid >> 6;      // wave id -> q-row group
    const int l15  = lane & 15;
    const int l4   = lane >> 4;
    const int r    = tid >> 2;      // staging row 0..63
    const int c4   = tid & 3;       // staging 16-elem chunk
    const int h = blockIdx.y, b = blockIdx.z;
    unsigned short* Pw = Pl + wq * (16 * 64);

#pragma unroll 1
    for (int qp = 0; qp < 2; ++qp) {
        const int qt = qp ? (31 - (int)blockIdx.x) : (int)blockIdx.x;
        // wave's Q rows -> registers (A-fragment layout: row=l15, k-slot=l4*8)
        short8 qf0, qf1;
        {
            const unsigned short* qb = Qp + ((size_t)(b * S_LEN + qt * 64 + wq * 16 + l15)) * DMODEL
                                          + h * HDIM + l4 * 8;
            qf0 = *(const short8*)qb;
            qf1 = *(const short8*)(qb + 32);
        }
        f32x4 oacc[4];
        float mrow[4], lrow[4];
#pragma unroll
        for (int t = 0; t < 4; ++t) oacc[t] = (f32x4){0.f,0.f,0.f,0.f};
#pragma unroll
        for (int i = 0; i < 4; ++i) { mrow[i] = -1e30f; lrow[i] = 0.f; }

#pragma unroll 1
        for (int kt = 0; kt <= qt; ++kt) {
            __syncthreads();   // previous tile's fragment reads done
            {   // stage K tile + transposed V tile
                const size_t gb = ((size_t)(b * S_LEN + kt * 64 + r)) * DMODEL + h * HDIM + c4 * 16;
                uint4 k0 = *(const uint4*)(Kp + gb);
                uint4 k1 = *(const uint4*)(Kp + gb + 8);
                uint4 v0 = *(const uint4*)(Vp + gb);
                uint4 v1 = *(const uint4*)(Vp + gb + 8);
                *(uint4*)swzp(Ks, r, c4 * 16)     = k0;
                *(uint4*)swzp(Ks, r, c4 * 16 + 8) = k1;
                const unsigned short* vs = (const unsigned short*)&v0;
#pragma unroll
                for (int j = 0; j < 8; ++j) *swzp(Vt, c4 * 16 + j, r) = vs[j];
                vs = (const unsigned short*)&v1;
#pragma unroll
                for (int j = 0; j < 8; ++j) *swzp(Vt, c4 * 16 + 8 + j, r) = vs[j];
            }
            __syncthreads();

            // QK^T: sc[t] = 16(q) x 16(key) scores for key sub-tile t
            f32x4 sc[4];
#pragma unroll
            for (int t = 0; t < 4; ++t) sc[t] = (f32x4){0.f,0.f,0.f,0.f};
#pragma unroll
            for (int t = 0; t < 4; ++t) {
                short8 kf = *(const short8*)swzp(Ks, t * 16 + l15, l4 * 8);
                sc[t] = __builtin_amdgcn_mfma_f32_16x16x32_bf16(qf0, kf, sc[t], 0, 0, 0);
            }
#pragma unroll
            for (int t = 0; t < 4; ++t) {
                short8 kf = *(const short8*)swzp(Ks, t * 16 + l15, 32 + l4 * 8);
                sc[t] = __builtin_amdgcn_mfma_f32_16x16x32_bf16(qf1, kf, sc[t], 0, 0, 0);
            }
            // scale + causal mask (value at lane: q=wq*16+l4*4+i, k=t*16+l15)
            const bool diag = (kt == qt);
#pragma unroll
            for (int t = 0; t < 4; ++t)
#pragma unroll
                for (int i = 0; i < 4; ++i) {
                    float s = sc[t][i] * 0.125f;
                    if (diag && (t * 16 + l15 > wq * 16 + l4 * 4 + i)) s = -1e30f;
                    sc[t][i] = s;
                }
            // online softmax per owned row i (row-group = 16 lanes sharing l4)
#pragma unroll
            for (int i = 0; i < 4; ++i) {
                float mx = fmaxf(fmaxf(sc[0][i], sc[1][i]), fmaxf(sc[2][i], sc[3][i]));
                mx = fmaxf(mx, __shfl_xor(mx, 1));
                mx = fmaxf(mx, __shfl_xor(mx, 2));
                mx = fmaxf(mx, __shfl_xor(mx, 4));
                mx = fmaxf(mx, __shfl_xor(mx, 8));
                const float mn = fmaxf(mrow[i], mx);
                const float al = __expf(mrow[i] - mn);   // first tile: 0
                mrow[i] = mn;
                float ls = 0.f;
#pragma unroll
                for (int t = 0; t < 4; ++t) {
                    float p = __expf(sc[t][i] - mn);
                    sc[t][i] = p;
                    ls += p;
                }
                ls += __shfl_xor(ls, 1);
                ls += __shfl_xor(ls, 2);
                ls += __shfl_xor(ls, 4);
                ls += __shfl_xor(ls, 8);
                lrow[i] = lrow[i] * al + ls;
#pragma unroll
                for (int t = 0; t < 4; ++t) oacc[t][i] *= al;
            }
            // P (C-layout) -> wave-private LDS -> A-fragment layout; wave-local, no barrier
#pragma unroll
            for (int t = 0; t < 4; ++t)
#pragma unroll
                for (int i = 0; i < 4; ++i)
                    *swzp(Pw, l4 * 4 + i, t * 16 + l15) = f2b(sc[t][i]);

            short8 pf0 = *(const short8*)swzp(Pw, l15, l4 * 8);
            short8 pf1 = *(const short8*)swzp(Pw, l15, 32 + l4 * 8);
            // PV: O[q][d] += P[q][k] V[k][d], B-operand = V^T rows
#pragma unroll
            for (int td = 0; td < 4; ++td) {
                short8 vf = *(const short8*)swzp(Vt, td * 16 + l15, l4 * 8);
                oacc[td] = __builtin_amdgcn_mfma_f32_16x16x32_bf16(pf0, vf, oacc[td], 0, 0, 0);
            }
#pragma unroll
            for (int td = 0; td < 4; ++td) {
                short8 vf = *(const short8*)swzp(Vt, td * 16 + l15, 32 + l4 * 8);
                oacc[td] = __builtin_amdgcn_mfma_f32_16x16x32_bf16(pf1, vf, oacc[td], 0, 0, 0);
            }
        }
        // epilogue: normalize + store (row=wq*16+l4*4+i, col=td*16+l15)
        float linv[4];
#pragma unroll
        for (int i = 0; i < 4; ++i) linv[i] = 1.0f / lrow[i];
        unsigned short* yb = Yp + ((size_t)(b * S_LEN + qt * 64 + wq * 16 + l4 * 4)) * DMODEL
                                + h * HDIM + l15;
#pragma unroll
        for (int i = 0; i < 4; ++i)
#pragma unroll
            for (int td = 0; td < 4; ++td)
                yb[(size_t)i * DMODEL + td * 16] = f2b(oacc[td][i] * linv[i]);
    }
}

extern "C" void kernel_launch(void* const* d_in, const int* in_sizes, int n_in,
                              void* d_out, int out_size, void* d_ws, size_t ws_size,
                              hipStream_t stream) {
    (void)in_sizes; (void)n_in; (void)out_size; (void)ws_size;
    const float* x  = (const float*)d_in[0];
    const float* Wq = (const float*)d_in[1];
    const float* Wk = (const float*)d_in[2];
    const float* Wv = (const float*)d_in[3];
    const float* Wo = (const float*)d_in[4];
    float* out = (float*)d_out;

    const size_t nx = (size_t)BATCH * S_LEN * DMODEL;   // 4,194,304
    const size_t nw = (size_t)DMODEL * DMODEL;          // 1,048,576
    char* ws = (char*)d_ws;
    unsigned short* xb  = (unsigned short*)ws; ws += nx * 2;
    unsigned short* wqb = (unsigned short*)ws; ws += nw * 2;
    unsigned short* wkb = (unsigned short*)ws; ws += nw * 2;
    unsigned short* wvb = (unsigned short*)ws; ws += nw * 2;
    unsigned short* wob = (unsigned short*)ws; ws += nw * 2;
    unsigned short* Qp  = (unsigned short*)ws; ws += nx * 2;
    unsigned short* Kp  = (unsigned short*)ws; ws += nx * 2;
    unsigned short* Vp  = (unsigned short*)ws; ws += nx * 2;
    unsigned short* yb  = (unsigned short*)ws; ws += nx * 2;  // total 48 MB

    cast_kernel<<<(int)(nx/4 + 255)/256, 256, 0, stream>>>(x,  xb,  (int)(nx/4));
    cast_kernel<<<(int)(nw/4 + 255)/256, 256, 0, stream>>>(Wq, wqb, (int)(nw/4));
    cast_kernel<<<(int)(nw/4 + 255)/256, 256, 0, stream>>>(Wk, wkb, (int)(nw/4));
    cast_kernel<<<(int)(nw/4 + 255)/256, 256, 0, stream>>>(Wv, wvb, (int)(nw/4));
    cast_kernel<<<(int)(nw/4 + 255)/256, 256, 0, stream>>>(Wo, wob, (int)(nw/4));

    dim3 gg(DMODEL / 64, (BATCH * S_LEN) / 64);
    gemm_nt<1><<<gg, 256, 0, stream>>>(xb, wqb, Qp, nullptr, BATCH*S_LEN, DMODEL, DMODEL);
    gemm_nt<1><<<gg, 256, 0, stream>>>(xb, wkb, Kp, nullptr, BATCH*S_LEN, DMODEL, DMODEL);
    gemm_nt<1><<<gg, 256, 0, stream>>>(xb, wvb, Vp, nullptr, BATCH*S_LEN, DMODEL, DMODEL);

    dim3 ga(S_LEN / 128, NHEADS, BATCH);   // 16 folded q-tile pairs
    attn_mfma<<<ga, 256, 0, stream>>>(Qp, Kp, Vp, yb);

    gemm_nt<0><<<gg, 256, 0, stream>>>(yb, wob, nullptr, out, BATCH*S_LEN, DMODEL, DMODEL);
}

// Round 6
// 241.249 us; speedup vs baseline: 6.6100x; 1.0151x over previous
//
#include <hip/hip_runtime.h>
#include <hip/hip_bf16.h>

// TinySelfAttention: x[2,2048,1024] fp32; Wq/Wk/Wv/Wo [1024,1024] fp32 ([out,in]).
// out = softmax_causal((xWq^T)(xWk^T)^T/8) (xWv^T) Wo^T, fp32.
//
// Pipeline: cast x -> bf16, cast 4 W -> bf16 (one kernel, contiguous dest) |
//           fused QKV MFMA GEMM (128^2 tile, global_load_lds) -> qkv[row][3072] |
//           bf16 MFMA flash attention -> y bf16 | MFMA GEMM y@Wo^T -> fp32 out.

#define S_LEN  2048
#define BATCH  2
#define DMODEL 1024
#define NHEADS 16
#define HDIM   64
#define QKV_LD 3072

typedef short short8 __attribute__((ext_vector_type(8)));
typedef float f32x4  __attribute__((ext_vector_type(4)));

__device__ __forceinline__ float b2f(unsigned short u) {
    union { unsigned int i; float f; } x; x.i = ((unsigned int)u) << 16; return x.f;
}
__device__ __forceinline__ unsigned short f2b(float f) {
    union { float f; unsigned int i; } x; x.f = f;
    unsigned int r = x.i + 0x7fffu + ((x.i >> 16) & 1u);  // RNE
    return (unsigned short)(r >> 16);
}

// async global->LDS, 16B per lane; LDS dest = wave-uniform base + lane*16 (HW rule)
__device__ __forceinline__ void gload16(const unsigned short* g, unsigned short* l) {
    __builtin_amdgcn_global_load_lds(
        (const __attribute__((address_space(1))) unsigned int*)g,
        (__attribute__((address_space(3))) unsigned int*)l, 16, 0, 0);
}

// XOR-swizzled accessor for 128B-row LDS tiles (attn; G4 bank-conflict fix).
__device__ __forceinline__ unsigned short* swzp(unsigned short* base, int row, int col) {
    int byte = (col << 1) ^ ((((row >> 3) ^ row) & 7) << 4);
    return base + (row << 6) + (byte >> 1);
}

// ---------------- cast fp32 -> bf16, 4 elems/thread ----------------
__global__ void cast_kernel(const float* __restrict__ in, unsigned short* __restrict__ out, int n4) {
    int i = blockIdx.x * blockDim.x + threadIdx.x;
    if (i >= n4) return;
    float4 v = ((const float4*)in)[i];
    unsigned int lo = (unsigned int)f2b(v.x) | ((unsigned int)f2b(v.y) << 16);
    unsigned int hi = (unsigned int)f2b(v.z) | ((unsigned int)f2b(v.w) << 16);
    ((uint2*)out)[i] = make_uint2(lo, hi);
}

// cast 4 weights (1M floats each) into one contiguous bf16 dest (wqkv | wo)
__global__ void cast_w4(const float* __restrict__ w0, const float* __restrict__ w1,
                        const float* __restrict__ w2, const float* __restrict__ w3,
                        unsigned short* __restrict__ out) {
    int i = blockIdx.x * blockDim.x + threadIdx.x;     // over 4M/4 = 1M float4
    if (i >= (1 << 20)) return;
    int seg = i >> 18;                                 // 2^18 float4 per weight
    const float* src = seg == 0 ? w0 : seg == 1 ? w1 : seg == 2 ? w2 : w3;
    float4 v = ((const float4*)src)[i & 0x3FFFF];
    unsigned int lo = (unsigned int)f2b(v.x) | ((unsigned int)f2b(v.y) << 16);
    unsigned int hi = (unsigned int)f2b(v.z) | ((unsigned int)f2b(v.w) << 16);
    ((uint2*)out)[i] = make_uint2(lo, hi);
}

// ---------------- bf16 MFMA GEMM: C[M,N] = A[M,K] @ W[N,K]^T ----------------
// m97 structure: 128x128 tile, BK=64, 256 threads (4 waves, 2x2 of 64x64),
// linear LDS + global_load_lds(16B), 2-barrier loop.
template<int OUT_BF16>
__global__ __launch_bounds__(256) void gemm128(const unsigned short* __restrict__ A,
                                               const unsigned short* __restrict__ W,
                                               unsigned short* __restrict__ Cb,
                                               float* __restrict__ Cf,
                                               int N, int K) {
    __shared__ unsigned short As[128 * 64];
    __shared__ unsigned short Bs[128 * 64];
    const int tid  = threadIdx.x;
    const int lane = tid & 63;
    const int wave = tid >> 6;
    const int bm = blockIdx.y * 128;
    const int bn = blockIdx.x * 128;
    const int wr = (wave >> 1) * 64;
    const int wc = (wave & 1) * 64;
    const int l15 = lane & 15;
    const int l4  = lane >> 4;

    // staging: wave w covers tile rows [w*32, w*32+32), 4 instrs x 8 rows each;
    // lane l -> row l>>3, col (l&7)*8 shorts (matches linear LDS base+lane*16B)
    const int srow = wave * 32 + (lane >> 3);
    const int scol = (lane & 7) * 8;
    const unsigned short* Ag = A + (size_t)(bm + srow) * K + scol;
    const unsigned short* Wg = W + (size_t)(bn + srow) * K + scol;
    unsigned short* Al = As + wave * 32 * 64;
    unsigned short* Bl = Bs + wave * 32 * 64;

    f32x4 acc[4][4];
#pragma unroll
    for (int i = 0; i < 4; ++i)
#pragma unroll
        for (int j = 0; j < 4; ++j) acc[i][j] = (f32x4){0.f, 0.f, 0.f, 0.f};

    for (int k0 = 0; k0 < K; k0 += 64) {
        __syncthreads();   // previous iteration's ds_reads done
#pragma unroll
        for (int i = 0; i < 4; ++i) {
            gload16(Ag + k0 + (size_t)(i * 8) * K, Al + i * 8 * 64);
            gload16(Wg + k0 + (size_t)(i * 8) * K, Bl + i * 8 * 64);
        }
        __syncthreads();   // drains vmcnt(0): staged data visible
#pragma unroll
        for (int kk = 0; kk < 2; ++kk) {
            short8 af[4], bf[4];
#pragma unroll
            for (int mi = 0; mi < 4; ++mi)
                af[mi] = *(const short8*)&As[(wr + mi * 16 + l15) * 64 + kk * 32 + l4 * 8];
#pragma unroll
            for (int ni = 0; ni < 4; ++ni)
                bf[ni] = *(const short8*)&Bs[(wc + ni * 16 + l15) * 64 + kk * 32 + l4 * 8];
#pragma unroll
            for (int mi = 0; mi < 4; ++mi)
#pragma unroll
                for (int ni = 0; ni < 4; ++ni)
                    acc[mi][ni] = __builtin_amdgcn_mfma_f32_16x16x32_bf16(af[mi], bf[ni], acc[mi][ni], 0, 0, 0);
        }
    }
    // epilogue: C/D layout col=lane&15, row=(lane>>4)*4+i (HW-verified)
#pragma unroll
    for (int mi = 0; mi < 4; ++mi)
#pragma unroll
        for (int ni = 0; ni < 4; ++ni)
#pragma unroll
            for (int i = 0; i < 4; ++i) {
                int row = bm + wr + mi * 16 + l4 * 4 + i;
                int col = bn + wc + ni * 16 + l15;
                float v = acc[mi][ni][i];
                if constexpr (OUT_BF16) Cb[(size_t)row * N + col] = f2b(v);
                else                    Cf[(size_t)row * N + col] = v;
            }
}

// ---------------- bf16 MFMA flash attention (causal) ----------------
// Block = (b, h, folded q-tile pair {f, 31-f}) -> uniform 33 kv-tiles/block.
// 4 waves x 16 q-rows. QK^T and PV on mfma_f32_16x16x32_bf16.
// Q/K/V read from interleaved qkv[row][3072]; K, V^T staged in swizzled LDS.
__global__ __launch_bounds__(256) void attn_mfma(const unsigned short* __restrict__ Qp,
                                                 const unsigned short* __restrict__ Kp,
                                                 const unsigned short* __restrict__ Vp,
                                                 unsigned short* __restrict__ Yp) {
    __shared__ unsigned short Ks[64 * 64];     // K[key][d]
    __shared__ unsigned short Vt[64 * 64];     // V^T[d][key]
    __shared__ unsigned short Pl[4 * 16 * 64]; // per-wave P[q][key]
    const int tid  = threadIdx.x;
    const int lane = tid & 63;
    const int wq   = tid >> 6;
    const int l15  = lane & 15;
    const int l4   = lane >> 4;
    const int r    = tid >> 2;
    const int c4   = tid & 3;
    const int h = blockIdx.y, b = blockIdx.z;
    unsigned short* Pw = Pl + wq * (16 * 64);

#pragma unroll 1
    for (int qp = 0; qp < 2; ++qp) {
        const int qt = qp ? (31 - (int)blockIdx.x) : (int)blockIdx.x;
        short8 qf0, qf1;
        {
            const unsigned short* qb = Qp + ((size_t)(b * S_LEN + qt * 64 + wq * 16 + l15)) * QKV_LD
                                          + h * HDIM + l4 * 8;
            qf0 = *(const short8*)qb;
            qf1 = *(const short8*)(qb + 32);
        }
        f32x4 oacc[4];
        float mrow[4], lrow[4];
#pragma unroll
        for (int t = 0; t < 4; ++t) oacc[t] = (f32x4){0.f, 0.f, 0.f, 0.f};
#pragma unroll
        for (int i = 0; i < 4; ++i) { mrow[i] = -1e30f; lrow[i] = 0.f; }

#pragma unroll 1
        for (int kt = 0; kt <= qt; ++kt) {
            __syncthreads();
            {   // stage K tile + transposed V tile
                const size_t gb = ((size_t)(b * S_LEN + kt * 64 + r)) * QKV_LD + h * HDIM + c4 * 16;
                uint4 k0 = *(const uint4*)(Kp + gb);
                uint4 k1 = *(const uint4*)(Kp + gb + 8);
                uint4 v0 = *(const uint4*)(Vp + gb);
                uint4 v1 = *(const uint4*)(Vp + gb + 8);
                *(uint4*)swzp(Ks, r, c4 * 16)     = k0;
                *(uint4*)swzp(Ks, r, c4 * 16 + 8) = k1;
                const unsigned short* vs = (const unsigned short*)&v0;
#pragma unroll
                for (int j = 0; j < 8; ++j) *swzp(Vt, c4 * 16 + j, r) = vs[j];
                vs = (const unsigned short*)&v1;
#pragma unroll
                for (int j = 0; j < 8; ++j) *swzp(Vt, c4 * 16 + 8 + j, r) = vs[j];
            }
            __syncthreads();

            f32x4 sc[4];
#pragma unroll
            for (int t = 0; t < 4; ++t) sc[t] = (f32x4){0.f, 0.f, 0.f, 0.f};
#pragma unroll
            for (int t = 0; t < 4; ++t) {
                short8 kf = *(const short8*)swzp(Ks, t * 16 + l15, l4 * 8);
                sc[t] = __builtin_amdgcn_mfma_f32_16x16x32_bf16(qf0, kf, sc[t], 0, 0, 0);
            }
#pragma unroll
            for (int t = 0; t < 4; ++t) {
                short8 kf = *(const short8*)swzp(Ks, t * 16 + l15, 32 + l4 * 8);
                sc[t] = __builtin_amdgcn_mfma_f32_16x16x32_bf16(qf1, kf, sc[t], 0, 0, 0);
            }
            const bool diag = (kt == qt);
#pragma unroll
            for (int t = 0; t < 4; ++t)
#pragma unroll
                for (int i = 0; i < 4; ++i) {
                    float s = sc[t][i] * 0.125f;
                    if (diag && (t * 16 + l15 > wq * 16 + l4 * 4 + i)) s = -1e30f;
                    sc[t][i] = s;
                }
#pragma unroll
            for (int i = 0; i < 4; ++i) {
                float mx = fmaxf(fmaxf(sc[0][i], sc[1][i]), fmaxf(sc[2][i], sc[3][i]));
                mx = fmaxf(mx, __shfl_xor(mx, 1));
                mx = fmaxf(mx, __shfl_xor(mx, 2));
                mx = fmaxf(mx, __shfl_xor(mx, 4));
                mx = fmaxf(mx, __shfl_xor(mx, 8));
                const float mn = fmaxf(mrow[i], mx);
                const float al = __expf(mrow[i] - mn);
                mrow[i] = mn;
                float ls = 0.f;
#pragma unroll
                for (int t = 0; t < 4; ++t) {
                    float p = __expf(sc[t][i] - mn);
                    sc[t][i] = p;
                    ls += p;
                }
                ls += __shfl_xor(ls, 1);
                ls += __shfl_xor(ls, 2);
                ls += __shfl_xor(ls, 4);
                ls += __shfl_xor(ls, 8);
                lrow[i] = lrow[i] * al + ls;
#pragma unroll
                for (int t = 0; t < 4; ++t) oacc[t][i] *= al;
            }
#pragma unroll
            for (int t = 0; t < 4; ++t)
#pragma unroll
                for (int i = 0; i < 4; ++i)
                    *swzp(Pw, l4 * 4 + i, t * 16 + l15) = f2b(sc[t][i]);

            short8 pf0 = *(const short8*)swzp(Pw, l15, l4 * 8);
            short8 pf1 = *(const short8*)swzp(Pw, l15, 32 + l4 * 8);
#pragma unroll
            for (int td = 0; td < 4; ++td) {
                short8 vf = *(const short8*)swzp(Vt, td * 16 + l15, l4 * 8);
                oacc[td] = __builtin_amdgcn_mfma_f32_16x16x32_bf16(pf0, vf, oacc[td], 0, 0, 0);
            }
#pragma unroll
            for (int td = 0; td < 4; ++td) {
                short8 vf = *(const short8*)swzp(Vt, td * 16 + l15, 32 + l4 * 8);
                oacc[td] = __builtin_amdgcn_mfma_f32_16x16x32_bf16(pf1, vf, oacc[td], 0, 0, 0);
            }
        }
        float linv[4];
#pragma unroll
        for (int i = 0; i < 4; ++i) linv[i] = 1.0f / lrow[i];
        unsigned short* yb = Yp + ((size_t)(b * S_LEN + qt * 64 + wq * 16 + l4 * 4)) * DMODEL
                                + h * HDIM + l15;
#pragma unroll
        for (int i = 0; i < 4; ++i)
#pragma unroll
            for (int td = 0; td < 4; ++td)
                yb[(size_t)i * DMODEL + td * 16] = f2b(oacc[td][i] * linv[i]);
    }
}

extern "C" void kernel_launch(void* const* d_in, const int* in_sizes, int n_in,
                              void* d_out, int out_size, void* d_ws, size_t ws_size,
                              hipStream_t stream) {
    (void)in_sizes; (void)n_in; (void)out_size; (void)ws_size;
    const float* x  = (const float*)d_in[0];
    const float* Wq = (const float*)d_in[1];
    const float* Wk = (const float*)d_in[2];
    const float* Wv = (const float*)d_in[3];
    const float* Wo = (const float*)d_in[4];
    float* out = (float*)d_out;

    const size_t nx = (size_t)BATCH * S_LEN * DMODEL;   // 4,194,304
    const size_t nw = (size_t)DMODEL * DMODEL;          // 1,048,576
    char* ws = (char*)d_ws;
    unsigned short* xb    = (unsigned short*)ws; ws += nx * 2;          // 8 MB
    unsigned short* wqkvb = (unsigned short*)ws; ws += nw * 3 * 2;      // 6 MB (Wq|Wk|Wv rows)
    unsigned short* wob   = (unsigned short*)ws; ws += nw * 2;          // 2 MB (contiguous after wqkvb)
    unsigned short* qkv   = (unsigned short*)ws; ws += nx * 3 * 2;      // 24 MB [row][3072]
    unsigned short* yb    = (unsigned short*)ws; ws += nx * 2;          // 8 MB  -> 48 MB total

    cast_kernel<<<(int)(nx / 4 + 255) / 256, 256, 0, stream>>>(x, xb, (int)(nx / 4));
    cast_w4<<<(1 << 20) / 256, 256, 0, stream>>>(Wq, Wk, Wv, Wo, wqkvb);  // dest = wqkv|wo

    dim3 gq(QKV_LD / 128, (BATCH * S_LEN) / 128);   // 24 x 32
    gemm128<1><<<gq, 256, 0, stream>>>(xb, wqkvb, qkv, nullptr, QKV_LD, DMODEL);

    dim3 ga(S_LEN / 128, NHEADS, BATCH);            // 16 folded q-tile pairs
    attn_mfma<<<ga, 256, 0, stream>>>(qkv, qkv + DMODEL, qkv + 2 * DMODEL, yb);

    dim3 go(DMODEL / 128, (BATCH * S_LEN) / 128);   // 8 x 32
    gemm128<0><<<go, 256, 0, stream>>>(yb, wob, nullptr, out, DMODEL, DMODEL);
}